// Round 9
// baseline (202.494 us; speedup 1.0000x reference)
//
#include <hip/hip_runtime.h>
#include <hip/hip_bf16.h>

// DLRM forward. MLP GEMMs on MFMA via bf16x3 split emulation.
// Two-level union-grid pipelining:
//   Phase A: bottom MLP + converts || gather of batch-half H1 (b < 2048)
//   Phase B: interact/top0/top1 of H1 || gather of batch-half H2
//   Tail:    interact/top0/top1 of H2 + final (full batch)
// Gather pairs are remapped per half: p in [0, 26*2048), t = p>>11,
// b = (p & 2047) + boff. Proven round-3 per-wave access pattern throughout.

constexpr int T_ = 26;
constexpr int N_ = 100000;
constexpr int D_ = 64;
constexpr int B_ = 4096;
constexpr int L_ = 32;
constexpr int NCAT = T_ + 1;                 // 27
constexpr int NPAIR = NCAT * (NCAT - 1) / 2; // 351
constexpr int RDIM = D_ + NPAIR;             // 415
constexpr int RPAD = 448;                    // padded to x64 for MFMA K-loop

constexpr int HB = 2048;                     // half batch
constexpr int HPAIRS = T_ * HB;              // 53248 pairs per half
constexpr int HUNITS = HPAIRS / 4;           // 13312 four-wave units per half
// chunk split per half across 3 carrier kernels
constexpr int CA1 = 4437, CA2 = 4437, CA3 = HUNITS - CA1 - CA2;  // phase A
constexpr int CB1 = 4437, CB2 = 4437, CB3 = HUNITS - CB1 - CB2;  // phase B

using bf16x8 = __attribute__((ext_vector_type(8))) short;
using f32x4  = __attribute__((ext_vector_type(4))) float;

#define GLOAD_LDS16(g, l)  __builtin_amdgcn_global_load_lds(                    \
    (const __attribute__((address_space(1))) void*)(g),                         \
    (__attribute__((address_space(3))) void*)(l), 16, 0, 0)

__device__ __forceinline__ void split_bf16(float v, ushort& h, ushort& l) {
    __hip_bfloat16 hb = __float2bfloat16(v);
    float hf = __bfloat162float(hb);
    __hip_bfloat16 lb = __float2bfloat16(v - hf);
    h = __builtin_bit_cast(ushort, hb);
    l = __builtin_bit_cast(ushort, lb);
}

// ---------------------------------------------------------------------------
// Gather block body: 4 waves, one (t,b) pair per wave; lane = d.
// Half-batch pair mapping: p -> t = p>>11, b = (p & 2047) + boff.
// ---------------------------------------------------------------------------
__device__ __forceinline__ void gather_block(
    const int* __restrict__ idx, const float* __restrict__ tables,
    float* __restrict__ Tcat, int pair0, int boff)
{
    const int w = threadIdx.x >> 6;
    const int d = threadIdx.x & 63;
    const int p = pair0 + w;
    if (p >= HPAIRS) return;
    const int t = p >> 11;
    const int b = (p & (HB - 1)) + boff;

    const int* ip = idx + ((size_t)t * B_ + b) * L_;
    const float* tab = tables + (size_t)t * N_ * D_;

    int rows[L_];
    #pragma unroll
    for (int l = 0; l < L_; ++l) rows[l] = ip[l];

    float s = 0.f;
    #pragma unroll
    for (int l = 0; l < L_; ++l)
        s += tab[(size_t)rows[l] * D_ + d];

    Tcat[((size_t)b * NCAT + 1 + t) * D_ + d] = s;
}

// ---------------------------------------------------------------------------
// K1: gemm13 (512 blocks) | convert_all (1984 blocks) | gather H1 chunk 1.
// ---------------------------------------------------------------------------
__global__ __launch_bounds__(256) void fused_l0_convert_gather(
    const float* __restrict__ A, const float* __restrict__ W0,
    const float* __restrict__ b0, ushort* __restrict__ Ch, ushort* __restrict__ Cl,
    const float* __restrict__ bW1, const float* __restrict__ bW2,
    const float* __restrict__ tW0, const float* __restrict__ tW1,
    ushort* __restrict__ h0, ushort* __restrict__ l0,
    ushort* __restrict__ h1, ushort* __restrict__ l1,
    ushort* __restrict__ h2, ushort* __restrict__ l2,
    ushort* __restrict__ h3, ushort* __restrict__ l3,
    const int* __restrict__ gidx, const float* __restrict__ gtab,
    float* __restrict__ gTcat)
{
    const int bx = blockIdx.x;
    if (bx >= 512 + 1984) {                  // ---- gather H1 chunk 1 ----
        gather_block(gidx, gtab, gTcat, (bx - 2496) * 4, 0);
        return;
    }
    if (bx >= 512) {                         // ---- weight converts ----
        int i = (bx - 512) * 256 + threadIdx.x;
        float v; ushort* ph; ushort* pl; int o;
        if (i < 131072) {
            v = bW1[i]; ph = h0; pl = l0; o = i;
        } else if (i < 147456) {
            o = i - 131072; v = bW2[o]; ph = h1; pl = l1;
        } else if (i < 376832) {
            o = i - 147456;
            int n = o / RPAD, k = o % RPAD;
            v = (k < RDIM) ? tW0[(size_t)n * RDIM + k] : 0.f;
            ph = h2; pl = l2;
        } else {
            o = i - 376832; v = tW1[o]; ph = h3; pl = l3;
        }
        ushort h, l;
        split_bf16(v, h, l);
        ph[o] = h; pl[o] = l;
        return;
    }
    // ---- gemm13: C = relu(dense_x @ W0^T + b0), K=13, split-bf16 out ----
    constexpr int K = 13;
    __shared__ float As[K][64 + 4];
    __shared__ float Ws[K][64 + 4];

    const int m0 = (bx & 63) * 64;           // 512 = 64 x 8
    const int n0 = (bx >> 6) * 64;
    const int tid = threadIdx.x;
    const int tx = tid % 16;
    const int ty = tid / 16;

    for (int e = tid; e < 64 * K; e += 256) {
        int m = e / K, k = e % K;
        As[k][m] = A[(size_t)(m0 + m) * K + k];
        Ws[k][m] = W0[(size_t)(n0 + m) * K + k];
    }
    __syncthreads();

    float acc[4][4] = {};
    #pragma unroll
    for (int k = 0; k < K; ++k) {
        float4 a4 = *reinterpret_cast<const float4*>(&As[k][ty * 4]);
        float4 w4 = *reinterpret_cast<const float4*>(&Ws[k][tx * 4]);
        float av[4] = {a4.x, a4.y, a4.z, a4.w};
        float wv[4] = {w4.x, w4.y, w4.z, w4.w};
        #pragma unroll
        for (int i = 0; i < 4; ++i)
            #pragma unroll
            for (int j = 0; j < 4; ++j)
                acc[i][j] = fmaf(av[i], wv[j], acc[i][j]);
    }

    #pragma unroll
    for (int i = 0; i < 4; ++i) {
        int row = m0 + ty * 4 + i;
        #pragma unroll
        for (int j = 0; j < 4; ++j) {
            int col = n0 + tx * 4 + j;
            float v = fmaxf(acc[i][j] + b0[col], 0.f);
            ushort h, lo_;
            split_bf16(v, h, lo_);
            Ch[(size_t)row * 512 + col] = h;
            Cl[(size_t)row * 512 + col] = lo_;
        }
    }
}

// ---------------------------------------------------------------------------
// MFMA GEMM, bf16x3 (round-7 proven structure), gather blocks appended.
// m-tiles = 1<<mshift; block bx: m0 = (bx & (mt-1))*64, n0 = (bx>>mshift)*64.
// EPI: 0 = fp32 C[ldc], 1 = split bf16 Ch/Cl[ldc].
// ---------------------------------------------------------------------------
template <int EPI>
__global__ __launch_bounds__(256) void gemm_mfma_x3_g(
    const ushort* __restrict__ Ah, const ushort* __restrict__ Al,
    const ushort* __restrict__ Wh, const ushort* __restrict__ Wl,
    const float* __restrict__ bias,
    float* __restrict__ Cf, ushort* __restrict__ Ch, ushort* __restrict__ Cl,
    int K, int lda, int ldw, int ldc, int mshift, int ngemm,
    const int* __restrict__ gidx, const float* __restrict__ gtab,
    float* __restrict__ gTcat, int gpair0, int gboff)
{
    const int bx = blockIdx.x;
    if (bx >= ngemm) {
        gather_block(gidx, gtab, gTcat, gpair0 + (bx - ngemm) * 4, gboff);
        return;
    }

    __shared__ alignas(16) ushort smAh[64 * 64], smAl[64 * 64],
                                  smWh[64 * 64], smWl[64 * 64];

    const int m0 = (bx & ((1 << mshift) - 1)) * 64;
    const int n0 = (bx >> mshift) * 64;
    const int tid = threadIdx.x;
    const int l = tid & 63;
    const int wv = tid >> 6;
    const int wm = wv >> 1, wn = wv & 1;

    f32x4 acc[2][2] = {};

    // staging: 512 16B chunks/tile; chunk ch: r=ch>>3, s=ch&7;
    // source col = s^(r&7) (inverse swizzle -> LDS content matches reads).
    int srcoff[2], ldsoff[2];
    #pragma unroll
    for (int c = 0; c < 2; ++c) {
        int ch = (wv * 2 + c) * 64 + l;
        int r = ch >> 3, s = ch & 7;
        srcoff[c] = r;
        ldsoff[c] = (s ^ (r & 7)) * 8;
    }
    const int base0 = (wv * 2 + 0) * 512;
    const int base1 = (wv * 2 + 1) * 512;

    for (int k0 = 0; k0 < K; k0 += 64) {
        {
            const size_t a0 = (size_t)(m0 + srcoff[0]) * lda + k0 + ldsoff[0];
            const size_t a1 = (size_t)(m0 + srcoff[1]) * lda + k0 + ldsoff[1];
            const size_t w0 = (size_t)(n0 + srcoff[0]) * ldw + k0 + ldsoff[0];
            const size_t w1 = (size_t)(n0 + srcoff[1]) * ldw + k0 + ldsoff[1];
            GLOAD_LDS16(Ah + a0, &smAh[base0]);
            GLOAD_LDS16(Ah + a1, &smAh[base1]);
            GLOAD_LDS16(Al + a0, &smAl[base0]);
            GLOAD_LDS16(Al + a1, &smAl[base1]);
            GLOAD_LDS16(Wh + w0, &smWh[base0]);
            GLOAD_LDS16(Wh + w1, &smWh[base1]);
            GLOAD_LDS16(Wl + w0, &smWl[base0]);
            GLOAD_LDS16(Wl + w1, &smWl[base1]);
        }
        __syncthreads();

        #pragma unroll
        for (int ks = 0; ks < 2; ++ks) {
            bf16x8 ah[2], al[2], bh[2], bl[2];
            #pragma unroll
            for (int fm = 0; fm < 2; ++fm) {
                int ar = wm * 32 + fm * 16 + (l & 15);
                int slot = (ks * 4 + (l >> 4)) ^ (ar & 7);
                ah[fm] = *(const bf16x8*)&smAh[ar * 64 + slot * 8];
                al[fm] = *(const bf16x8*)&smAl[ar * 64 + slot * 8];
            }
            #pragma unroll
            for (int fn = 0; fn < 2; ++fn) {
                int wr = wn * 32 + fn * 16 + (l & 15);
                int slot = (ks * 4 + (l >> 4)) ^ (wr & 7);
                bh[fn] = *(const bf16x8*)&smWh[wr * 64 + slot * 8];
                bl[fn] = *(const bf16x8*)&smWl[wr * 64 + slot * 8];
            }
            #pragma unroll
            for (int fm = 0; fm < 2; ++fm)
                #pragma unroll
                for (int fn = 0; fn < 2; ++fn) {
                    acc[fm][fn] = __builtin_amdgcn_mfma_f32_16x16x32_bf16(ah[fm], bh[fn], acc[fm][fn], 0, 0, 0);
                    acc[fm][fn] = __builtin_amdgcn_mfma_f32_16x16x32_bf16(ah[fm], bl[fn], acc[fm][fn], 0, 0, 0);
                    acc[fm][fn] = __builtin_amdgcn_mfma_f32_16x16x32_bf16(al[fm], bh[fn], acc[fm][fn], 0, 0, 0);
                }
        }
        __syncthreads();
    }

    // C/D frag mapping: col = l&15, row = (l>>4)*4 + j  [m89]
    #pragma unroll
    for (int fm = 0; fm < 2; ++fm)
        #pragma unroll
        for (int fn = 0; fn < 2; ++fn) {
            int gcol = n0 + wn * 32 + fn * 16 + (l & 15);
            float bv = bias[gcol];
            #pragma unroll
            for (int j = 0; j < 4; ++j) {
                int grow = m0 + wm * 32 + fm * 16 + (l >> 4) * 4 + j;
                float v = fmaxf(acc[fm][fn][j] + bv, 0.f);
                if (EPI == 0) {
                    Cf[(size_t)grow * ldc + gcol] = v;
                } else {
                    ushort h, lo_;
                    split_bf16(v, h, lo_);
                    Ch[(size_t)grow * ldc + gcol] = h;
                    Cl[(size_t)grow * ldc + gcol] = lo_;
                }
            }
        }
}

// ---------------------------------------------------------------------------
// Pairwise interaction for a half batch (rows boff..boff+2047), 256 threads,
// gather blocks appended. LDS transposed stride-29 -> conflict-free dot loop.
// ---------------------------------------------------------------------------
__global__ __launch_bounds__(256) void interact_g(
    const float* __restrict__ Tcat, ushort* __restrict__ Rh, ushort* __restrict__ Rl,
    int boff_i, int ninter,
    const int* __restrict__ gidx, const float* __restrict__ gtab,
    float* __restrict__ gTcat, int gpair0, int gboff)
{
    const int bx = blockIdx.x;
    if (bx >= ninter) {
        gather_block(gidx, gtab, gTcat, gpair0 + (bx - ninter) * 4, gboff);
        return;
    }
    const int b = bx + boff_i;
    __shared__ float tc[D_ * 29];
    const int tid = threadIdx.x;

    for (int e = tid; e < NCAT * D_; e += 256) {
        int i = e / D_, d = e % D_;
        tc[d * 29 + i] = Tcat[(size_t)b * NCAT * D_ + e];
    }
    __syncthreads();

    if (tid < D_) {
        ushort h, lo_;
        split_bf16(Tcat[(size_t)b * NCAT * D_ + tid], h, lo_);
        Rh[(size_t)b * RPAD + tid] = h;
        Rl[(size_t)b * RPAD + tid] = lo_;
    }
    if (tid < RPAD - RDIM) {
        Rh[(size_t)b * RPAD + RDIM + tid] = 0;
        Rl[(size_t)b * RPAD + RDIM + tid] = 0;
    }

    for (int p = tid; p < NPAIR; p += 256) {
        int i = (int)((1.0f + sqrtf(1.0f + 8.0f * (float)p)) * 0.5f);
        while (i * (i - 1) / 2 > p) --i;
        while ((i + 1) * i / 2 <= p) ++i;
        int j = p - i * (i - 1) / 2;
        float s = 0.f;
        #pragma unroll
        for (int d = 0; d < D_; ++d)
            s = fmaf(tc[d * 29 + i], tc[d * 29 + j], s);
        ushort h, lo_;
        split_bf16(s, h, lo_);
        Rh[(size_t)b * RPAD + D_ + p] = h;
        Rl[(size_t)b * RPAD + D_ + p] = lo_;
    }
}

// ---------------------------------------------------------------------------
// Final layer: out[b] = relu(dot(A[b], W[0]) + bias[0]), K=256 fp32
// ---------------------------------------------------------------------------
__global__ __launch_bounds__(256) void final_layer(
    const float* __restrict__ A, const float* __restrict__ W,
    const float* __restrict__ bias, float* __restrict__ out)
{
    const int b = blockIdx.x * 4 + threadIdx.x / 64;
    const int lane = threadIdx.x % 64;
    const float* a = A + (size_t)b * 256;
    float s = 0.f;
    #pragma unroll
    for (int k = lane; k < 256; k += 64) s = fmaf(a[k], W[k], s);
    #pragma unroll
    for (int off = 32; off > 0; off >>= 1) s += __shfl_down(s, off);
    if (lane == 0) out[b] = fmaxf(s + bias[0], 0.f);
}

// ---------------------------------------------------------------------------

extern "C" void kernel_launch(void* const* d_in, const int* in_sizes, int n_in,
                              void* d_out, int out_size, void* d_ws, size_t ws_size,
                              hipStream_t stream)
{
    const float* dense_x = (const float*)d_in[0];
    const int*   indices = (const int*)d_in[1];
    const float* tables  = (const float*)d_in[2];
    const float* bot_W0  = (const float*)d_in[3];
    const float* bot_b0  = (const float*)d_in[4];
    const float* bot_W1  = (const float*)d_in[5];
    const float* bot_b1  = (const float*)d_in[6];
    const float* bot_W2  = (const float*)d_in[7];
    const float* bot_b2  = (const float*)d_in[8];
    const float* top_W0  = (const float*)d_in[9];
    const float* top_b0  = (const float*)d_in[10];
    const float* top_W1  = (const float*)d_in[11];
    const float* top_b1  = (const float*)d_in[12];
    const float* top_W2  = (const float*)d_in[13];
    const float* top_b2  = (const float*)d_in[14];
    float* out = (float*)d_out;

    // workspace layout (256B-aligned regions)
    char* base = (char*)d_ws;
    size_t off = 0;
    auto alloc = [&](size_t bytes) { char* p = base + off; off = (off + bytes + 255) & ~(size_t)255; return p; };
    float*  tcat  = (float*) alloc((size_t)B_ * NCAT * D_ * 4);   // 28.3 MB
    float*  buf2f = (float*) alloc((size_t)B_ * 256 * 4);         // 4 MB
    ushort* b1h   = (ushort*)alloc((size_t)B_ * 512 * 2);         // 4 MB
    ushort* b1l   = (ushort*)alloc((size_t)B_ * 512 * 2);
    ushort* b2h   = (ushort*)alloc((size_t)B_ * 256 * 2);         // 2 MB
    ushort* b2l   = (ushort*)alloc((size_t)B_ * 256 * 2);
    ushort* Rh    = (ushort*)alloc((size_t)B_ * RPAD * 2);        // 3.7 MB
    ushort* Rl    = (ushort*)alloc((size_t)B_ * RPAD * 2);
    ushort* wb1h  = (ushort*)alloc((size_t)256 * 512 * 2);
    ushort* wb1l  = (ushort*)alloc((size_t)256 * 512 * 2);
    ushort* wb2h  = (ushort*)alloc((size_t)64 * 256 * 2);
    ushort* wb2l  = (ushort*)alloc((size_t)64 * 256 * 2);
    ushort* wt0h  = (ushort*)alloc((size_t)512 * RPAD * 2);
    ushort* wt0l  = (ushort*)alloc((size_t)512 * RPAD * 2);
    ushort* wt1h  = (ushort*)alloc((size_t)256 * 512 * 2);
    ushort* wt1l  = (ushort*)alloc((size_t)256 * 512 * 2);

    // ---- Phase A: bottom MLP + converts || gather H1 (boff 0) ----
    fused_l0_convert_gather<<<512 + 1984 + CA1, 256, 0, stream>>>(
        dense_x, bot_W0, bot_b0, b1h, b1l,
        bot_W1, bot_W2, top_W0, top_W1,
        wb1h, wb1l, wb2h, wb2l, wt0h, wt0l, wt1h, wt1l,
        indices, tables, tcat);
    // l1 (4096x256, K=512; 64 mt x 4 nt = 256 gemm blocks)
    gemm_mfma_x3_g<1><<<256 + CA2, 256, 0, stream>>>(
        b1h, b1l, wb1h, wb1l, bot_b1, nullptr, b2h, b2l,
        512, 512, 512, 256, 6, 256,
        indices, tables, tcat, CA1 * 4, 0);
    // l2 (4096x64, K=256; 64 mt x 1 nt = 64 gemm blocks)
    gemm_mfma_x3_g<0><<<64 + CA3, 256, 0, stream>>>(
        b2h, b2l, wb2h, wb2l, bot_b2, tcat, nullptr, nullptr,
        256, 256, 256, NCAT * D_, 6, 64,
        indices, tables, tcat, (CA1 + CA2) * 4, 0);

    // ---- Phase B: H1 interact/top || gather H2 (boff 2048) ----
    interact_g<<<HB + CB1, 256, 0, stream>>>(
        tcat, Rh, Rl, 0, HB,
        indices, tables, tcat, 0, HB);
    // top0 H1 (2048x512, K=448; 32 mt x 8 nt = 256 gemm blocks)
    gemm_mfma_x3_g<1><<<256 + CB2, 256, 0, stream>>>(
        Rh, Rl, wt0h, wt0l, top_b0, nullptr, b1h, b1l,
        RPAD, RPAD, RPAD, 512, 5, 256,
        indices, tables, tcat, CB1 * 4, HB);
    // top1 H1 (2048x256, K=512; 32 mt x 4 nt = 128 gemm blocks)
    gemm_mfma_x3_g<0><<<128 + CB3, 256, 0, stream>>>(
        b1h, b1l, wt1h, wt1l, top_b1, buf2f, nullptr, nullptr,
        512, 512, 512, 256, 5, 128,
        indices, tables, tcat, (CB1 + CB2) * 4, HB);

    // ---- Tail: H2 interact/top + final ----
    interact_g<<<HB, 256, 0, stream>>>(
        tcat, Rh, Rl, HB, HB,
        indices, tables, tcat, HUNITS * 4, HB);  // no gather blocks (grid == ninter)
    gemm_mfma_x3_g<1><<<256, 256, 0, stream>>>(
        Rh + (size_t)HB * RPAD, Rl + (size_t)HB * RPAD, wt0h, wt0l, top_b0,
        nullptr, b1h + (size_t)HB * 512, b1l + (size_t)HB * 512,
        RPAD, RPAD, RPAD, 512, 5, 256,
        indices, tables, tcat, 0, HB);
    gemm_mfma_x3_g<0><<<128, 256, 0, stream>>>(
        b1h + (size_t)HB * 512, b1l + (size_t)HB * 512, wt1h, wt1l, top_b1,
        buf2f + (size_t)HB * 256, nullptr, nullptr,
        512, 512, 512, 256, 5, 128,
        indices, tables, tcat, 0, HB);
    final_layer<<<B_ / 4, 256, 0, stream>>>(buf2f, top_W2, top_b2, out);
}

// Round 10
// 187.506 us; speedup vs baseline: 1.0799x; 1.0799x over previous
//
#include <hip/hip_runtime.h>
#include <hip/hip_bf16.h>

// DLRM forward. MLP GEMMs on MFMA via bf16x3 split emulation.
// Union-grid hybrids: the embedding gather (independent of the MLP chain) is
// split into 3 chunks appended to the bottom-MLP kernels' grids, so the
// bottom MLP + weight converts hide entirely under the gather's HBM time.
// (Round-8 proven configuration; round-9's batch-split variant regressed
// +15 us from cross-half table-row re-fetch — see journal.)

constexpr int T_ = 26;
constexpr int N_ = 100000;
constexpr int D_ = 64;
constexpr int B_ = 4096;
constexpr int L_ = 32;
constexpr int NCAT = T_ + 1;                 // 27
constexpr int NPAIR = NCAT * (NCAT - 1) / 2; // 351
constexpr int RDIM = D_ + NPAIR;             // 415
constexpr int RPAD = 448;                    // padded to x64 for MFMA K-loop

constexpr int GPAIRS = T_ * B_;              // 106496 gather (t,b) pairs
constexpr int GBLK   = GPAIRS / 4;           // 26624 four-wave block-units
constexpr int G1 = 8875, G2 = 8875, G3 = GBLK - G1 - G2;  // 8874

using bf16x8 = __attribute__((ext_vector_type(8))) short;
using f32x4  = __attribute__((ext_vector_type(4))) float;

#define GLOAD_LDS16(g, l)  __builtin_amdgcn_global_load_lds(                    \
    (const __attribute__((address_space(1))) void*)(g),                         \
    (__attribute__((address_space(3))) void*)(l), 16, 0, 0)

__device__ __forceinline__ void split_bf16(float v, ushort& h, ushort& l) {
    __hip_bfloat16 hb = __float2bfloat16(v);
    float hf = __bfloat162float(hb);
    __hip_bfloat16 lb = __float2bfloat16(v - hf);
    h = __builtin_bit_cast(ushort, hb);
    l = __builtin_bit_cast(ushort, lb);
}

// ---------------------------------------------------------------------------
// Gather block body: 4 waves, one (t,b) pair per wave; lane = d.
// Proven round-3 access pattern: 32 independent 256B row loads in flight.
// ---------------------------------------------------------------------------
__device__ __forceinline__ void gather_block(
    const int* __restrict__ idx, const float* __restrict__ tables,
    float* __restrict__ Tcat, int pair0)
{
    const int w = threadIdx.x >> 6;
    const int d = threadIdx.x & 63;
    const int p = pair0 + w;
    if (p >= GPAIRS) return;
    const int t = p >> 12;                   // p / 4096
    const int b = p & (B_ - 1);

    const int* ip = idx + ((size_t)t * B_ + b) * L_;
    const float* tab = tables + (size_t)t * N_ * D_;

    int rows[L_];
    #pragma unroll
    for (int l = 0; l < L_; ++l) rows[l] = ip[l];

    float s = 0.f;
    #pragma unroll
    for (int l = 0; l < L_; ++l)
        s += tab[(size_t)rows[l] * D_ + d];

    Tcat[((size_t)b * NCAT + 1 + t) * D_ + d] = s;
}

// ---------------------------------------------------------------------------
// Hybrid kernel 1: gemm13 (512 blocks) | convert_all (1984 blocks) | gather G1.
// ---------------------------------------------------------------------------
__global__ __launch_bounds__(256) void fused_l0_convert_gather(
    const float* __restrict__ A, const float* __restrict__ W0,
    const float* __restrict__ b0, ushort* __restrict__ Ch, ushort* __restrict__ Cl,
    const float* __restrict__ bW1, const float* __restrict__ bW2,
    const float* __restrict__ tW0, const float* __restrict__ tW1,
    ushort* __restrict__ h0, ushort* __restrict__ l0,
    ushort* __restrict__ h1, ushort* __restrict__ l1,
    ushort* __restrict__ h2, ushort* __restrict__ l2,
    ushort* __restrict__ h3, ushort* __restrict__ l3,
    const int* __restrict__ gidx, const float* __restrict__ gtab,
    float* __restrict__ gTcat)
{
    const int bx = blockIdx.x;
    if (bx >= 512 + 1984) {                  // ---- gather chunk 1 ----
        gather_block(gidx, gtab, gTcat, (bx - 2496) * 4);
        return;
    }
    if (bx >= 512) {                         // ---- weight converts ----
        int i = (bx - 512) * 256 + threadIdx.x;
        float v; ushort* ph; ushort* pl; int o;
        if (i < 131072) {
            v = bW1[i]; ph = h0; pl = l0; o = i;
        } else if (i < 147456) {
            o = i - 131072; v = bW2[o]; ph = h1; pl = l1;
        } else if (i < 376832) {
            o = i - 147456;
            int n = o / RPAD, k = o % RPAD;
            v = (k < RDIM) ? tW0[(size_t)n * RDIM + k] : 0.f;
            ph = h2; pl = l2;
        } else {
            o = i - 376832; v = tW1[o]; ph = h3; pl = l3;
        }
        ushort h, l;
        split_bf16(v, h, l);
        ph[o] = h; pl[o] = l;
        return;
    }
    // ---- gemm13: C = relu(dense_x @ W0^T + b0), K=13, split-bf16 out ----
    constexpr int K = 13;
    __shared__ float As[K][64 + 4];
    __shared__ float Ws[K][64 + 4];

    const int m0 = (bx & 63) * 64;           // 512 = 64 x 8
    const int n0 = (bx >> 6) * 64;
    const int tid = threadIdx.x;
    const int tx = tid % 16;
    const int ty = tid / 16;

    for (int e = tid; e < 64 * K; e += 256) {
        int m = e / K, k = e % K;
        As[k][m] = A[(size_t)(m0 + m) * K + k];
        Ws[k][m] = W0[(size_t)(n0 + m) * K + k];
    }
    __syncthreads();

    float acc[4][4] = {};
    #pragma unroll
    for (int k = 0; k < K; ++k) {
        float4 a4 = *reinterpret_cast<const float4*>(&As[k][ty * 4]);
        float4 w4 = *reinterpret_cast<const float4*>(&Ws[k][tx * 4]);
        float av[4] = {a4.x, a4.y, a4.z, a4.w};
        float wv[4] = {w4.x, w4.y, w4.z, w4.w};
        #pragma unroll
        for (int i = 0; i < 4; ++i)
            #pragma unroll
            for (int j = 0; j < 4; ++j)
                acc[i][j] = fmaf(av[i], wv[j], acc[i][j]);
    }

    #pragma unroll
    for (int i = 0; i < 4; ++i) {
        int row = m0 + ty * 4 + i;
        #pragma unroll
        for (int j = 0; j < 4; ++j) {
            int col = n0 + tx * 4 + j;
            float v = fmaxf(acc[i][j] + b0[col], 0.f);
            ushort h, lo_;
            split_bf16(v, h, lo_);
            Ch[(size_t)row * 512 + col] = h;
            Cl[(size_t)row * 512 + col] = lo_;
        }
    }
}

// ---------------------------------------------------------------------------
// MFMA GEMM, bf16x3 (round-7 proven: global_load_lds staging, stage->barrier->
// compute->barrier), with optional gather blocks appended to the grid.
// BM=BN=64, BK=64, 256 threads = 4 waves (2x2), 32x32 per wave.
// ngemm = #gemm blocks (64*nby); blocks beyond do gather from gpair0.
// EPI: 0 = fp32 C[ldc], 1 = split bf16 Ch/Cl[ldc].
// ---------------------------------------------------------------------------
template <int EPI>
__global__ __launch_bounds__(256) void gemm_mfma_x3_g(
    const ushort* __restrict__ Ah, const ushort* __restrict__ Al,
    const ushort* __restrict__ Wh, const ushort* __restrict__ Wl,
    const float* __restrict__ bias,
    float* __restrict__ Cf, ushort* __restrict__ Ch, ushort* __restrict__ Cl,
    int K, int lda, int ldw, int ldc, int ngemm,
    const int* __restrict__ gidx, const float* __restrict__ gtab,
    float* __restrict__ gTcat, int gpair0)
{
    const int bx = blockIdx.x;
    if (bx >= ngemm) {
        gather_block(gidx, gtab, gTcat, gpair0 + (bx - ngemm) * 4);
        return;
    }

    __shared__ alignas(16) ushort smAh[64 * 64], smAl[64 * 64],
                                  smWh[64 * 64], smWl[64 * 64];

    const int m0 = (bx & 63) * 64;
    const int n0 = (bx >> 6) * 64;
    const int tid = threadIdx.x;
    const int l = tid & 63;
    const int wv = tid >> 6;
    const int wm = wv >> 1, wn = wv & 1;

    f32x4 acc[2][2] = {};

    // staging: 512 16B chunks/tile; wave-call c of wave wv covers chunk
    // (wv*2+c)*64 + lane. chunk ch: r=ch>>3, s=ch&7; source col = s^(r&7)
    // (inverse swizzle -> LDS content matches swizzled read pattern).
    int srcoff[2], ldsoff[2];
    #pragma unroll
    for (int c = 0; c < 2; ++c) {
        int ch = (wv * 2 + c) * 64 + l;
        int r = ch >> 3, s = ch & 7;
        srcoff[c] = r;
        ldsoff[c] = (s ^ (r & 7)) * 8;
    }
    const int base0 = (wv * 2 + 0) * 512;
    const int base1 = (wv * 2 + 1) * 512;

    for (int k0 = 0; k0 < K; k0 += 64) {
        {
            const size_t a0 = (size_t)(m0 + srcoff[0]) * lda + k0 + ldsoff[0];
            const size_t a1 = (size_t)(m0 + srcoff[1]) * lda + k0 + ldsoff[1];
            const size_t w0 = (size_t)(n0 + srcoff[0]) * ldw + k0 + ldsoff[0];
            const size_t w1 = (size_t)(n0 + srcoff[1]) * ldw + k0 + ldsoff[1];
            GLOAD_LDS16(Ah + a0, &smAh[base0]);
            GLOAD_LDS16(Ah + a1, &smAh[base1]);
            GLOAD_LDS16(Al + a0, &smAl[base0]);
            GLOAD_LDS16(Al + a1, &smAl[base1]);
            GLOAD_LDS16(Wh + w0, &smWh[base0]);
            GLOAD_LDS16(Wh + w1, &smWh[base1]);
            GLOAD_LDS16(Wl + w0, &smWl[base0]);
            GLOAD_LDS16(Wl + w1, &smWl[base1]);
        }
        __syncthreads();

        #pragma unroll
        for (int ks = 0; ks < 2; ++ks) {
            bf16x8 ah[2], al[2], bh[2], bl[2];
            #pragma unroll
            for (int fm = 0; fm < 2; ++fm) {
                int ar = wm * 32 + fm * 16 + (l & 15);
                int slot = (ks * 4 + (l >> 4)) ^ (ar & 7);
                ah[fm] = *(const bf16x8*)&smAh[ar * 64 + slot * 8];
                al[fm] = *(const bf16x8*)&smAl[ar * 64 + slot * 8];
            }
            #pragma unroll
            for (int fn = 0; fn < 2; ++fn) {
                int wr = wn * 32 + fn * 16 + (l & 15);
                int slot = (ks * 4 + (l >> 4)) ^ (wr & 7);
                bh[fn] = *(const bf16x8*)&smWh[wr * 64 + slot * 8];
                bl[fn] = *(const bf16x8*)&smWl[wr * 64 + slot * 8];
            }
            #pragma unroll
            for (int fm = 0; fm < 2; ++fm)
                #pragma unroll
                for (int fn = 0; fn < 2; ++fn) {
                    acc[fm][fn] = __builtin_amdgcn_mfma_f32_16x16x32_bf16(ah[fm], bh[fn], acc[fm][fn], 0, 0, 0);
                    acc[fm][fn] = __builtin_amdgcn_mfma_f32_16x16x32_bf16(ah[fm], bl[fn], acc[fm][fn], 0, 0, 0);
                    acc[fm][fn] = __builtin_amdgcn_mfma_f32_16x16x32_bf16(al[fm], bh[fn], acc[fm][fn], 0, 0, 0);
                }
        }
        __syncthreads();
    }

    // C/D frag mapping: col = l&15, row = (l>>4)*4 + j  [m89]
    #pragma unroll
    for (int fm = 0; fm < 2; ++fm)
        #pragma unroll
        for (int fn = 0; fn < 2; ++fn) {
            int gcol = n0 + wn * 32 + fn * 16 + (l & 15);
            float bv = bias[gcol];
            #pragma unroll
            for (int j = 0; j < 4; ++j) {
                int grow = m0 + wm * 32 + fm * 16 + (l >> 4) * 4 + j;
                float v = fmaxf(acc[fm][fn][j] + bv, 0.f);
                if (EPI == 0) {
                    Cf[(size_t)grow * ldc + gcol] = v;
                } else {
                    ushort h, lo_;
                    split_bf16(v, h, lo_);
                    Ch[(size_t)grow * ldc + gcol] = h;
                    Cl[(size_t)grow * ldc + gcol] = lo_;
                }
            }
        }
}

// ---------------------------------------------------------------------------
// Pairwise interaction -> R split bf16, padded to RPAD.
// LDS transposed stride-29 (coprime to 32 banks) -> conflict-free dot loop.
// ---------------------------------------------------------------------------
__global__ __launch_bounds__(128) void interact_split(
    const float* __restrict__ Tcat, ushort* __restrict__ Rh, ushort* __restrict__ Rl)
{
    const int b = blockIdx.x;
    __shared__ float tc[D_ * 29];
    const int tid = threadIdx.x;

    for (int e = tid; e < NCAT * D_; e += 128) {
        int i = e / D_, d = e % D_;
        tc[d * 29 + i] = Tcat[(size_t)b * NCAT * D_ + e];
    }
    __syncthreads();

    if (tid < D_) {
        ushort h, lo_;
        split_bf16(Tcat[(size_t)b * NCAT * D_ + tid], h, lo_);
        Rh[(size_t)b * RPAD + tid] = h;
        Rl[(size_t)b * RPAD + tid] = lo_;
    }
    if (tid < RPAD - RDIM) {
        Rh[(size_t)b * RPAD + RDIM + tid] = 0;
        Rl[(size_t)b * RPAD + RDIM + tid] = 0;
    }

    for (int p = tid; p < NPAIR; p += 128) {
        int i = (int)((1.0f + sqrtf(1.0f + 8.0f * (float)p)) * 0.5f);
        while (i * (i - 1) / 2 > p) --i;
        while ((i + 1) * i / 2 <= p) ++i;
        int j = p - i * (i - 1) / 2;
        float s = 0.f;
        #pragma unroll
        for (int d = 0; d < D_; ++d)
            s = fmaf(tc[d * 29 + i], tc[d * 29 + j], s);
        ushort h, lo_;
        split_bf16(s, h, lo_);
        Rh[(size_t)b * RPAD + D_ + p] = h;
        Rl[(size_t)b * RPAD + D_ + p] = lo_;
    }
}

// ---------------------------------------------------------------------------
// Final layer: out[b] = relu(dot(A[b], W[0]) + bias[0]), K=256 fp32
// ---------------------------------------------------------------------------
__global__ __launch_bounds__(256) void final_layer(
    const float* __restrict__ A, const float* __restrict__ W,
    const float* __restrict__ bias, float* __restrict__ out)
{
    const int b = blockIdx.x * 4 + threadIdx.x / 64;
    const int lane = threadIdx.x % 64;
    const float* a = A + (size_t)b * 256;
    float s = 0.f;
    #pragma unroll
    for (int k = lane; k < 256; k += 64) s = fmaf(a[k], W[k], s);
    #pragma unroll
    for (int off = 32; off > 0; off >>= 1) s += __shfl_down(s, off);
    if (lane == 0) out[b] = fmaxf(s + bias[0], 0.f);
}

// ---------------------------------------------------------------------------

extern "C" void kernel_launch(void* const* d_in, const int* in_sizes, int n_in,
                              void* d_out, int out_size, void* d_ws, size_t ws_size,
                              hipStream_t stream)
{
    const float* dense_x = (const float*)d_in[0];
    const int*   indices = (const int*)d_in[1];
    const float* tables  = (const float*)d_in[2];
    const float* bot_W0  = (const float*)d_in[3];
    const float* bot_b0  = (const float*)d_in[4];
    const float* bot_W1  = (const float*)d_in[5];
    const float* bot_b1  = (const float*)d_in[6];
    const float* bot_W2  = (const float*)d_in[7];
    const float* bot_b2  = (const float*)d_in[8];
    const float* top_W0  = (const float*)d_in[9];
    const float* top_b0  = (const float*)d_in[10];
    const float* top_W1  = (const float*)d_in[11];
    const float* top_b1  = (const float*)d_in[12];
    const float* top_W2  = (const float*)d_in[13];
    const float* top_b2  = (const float*)d_in[14];
    float* out = (float*)d_out;

    // workspace layout (256B-aligned regions)
    char* base = (char*)d_ws;
    size_t off = 0;
    auto alloc = [&](size_t bytes) { char* p = base + off; off = (off + bytes + 255) & ~(size_t)255; return p; };
    float*  tcat  = (float*) alloc((size_t)B_ * NCAT * D_ * 4);   // 28.3 MB
    float*  buf2f = (float*) alloc((size_t)B_ * 256 * 4);         // 4 MB
    ushort* b1h   = (ushort*)alloc((size_t)B_ * 512 * 2);         // 4 MB
    ushort* b1l   = (ushort*)alloc((size_t)B_ * 512 * 2);
    ushort* b2h   = (ushort*)alloc((size_t)B_ * 256 * 2);         // 2 MB
    ushort* b2l   = (ushort*)alloc((size_t)B_ * 256 * 2);
    ushort* Rh    = (ushort*)alloc((size_t)B_ * RPAD * 2);        // 3.7 MB
    ushort* Rl    = (ushort*)alloc((size_t)B_ * RPAD * 2);
    ushort* wb1h  = (ushort*)alloc((size_t)256 * 512 * 2);
    ushort* wb1l  = (ushort*)alloc((size_t)256 * 512 * 2);
    ushort* wb2h  = (ushort*)alloc((size_t)64 * 256 * 2);
    ushort* wb2l  = (ushort*)alloc((size_t)64 * 256 * 2);
    ushort* wt0h  = (ushort*)alloc((size_t)512 * RPAD * 2);
    ushort* wt0l  = (ushort*)alloc((size_t)512 * RPAD * 2);
    ushort* wt1h  = (ushort*)alloc((size_t)256 * 512 * 2);
    ushort* wt1l  = (ushort*)alloc((size_t)256 * 512 * 2);

    // ---- hybrid 1: bottom l0 + all weight converts + gather chunk 1 ----
    fused_l0_convert_gather<<<512 + 1984 + G1, 256, 0, stream>>>(
        dense_x, bot_W0, bot_b0, b1h, b1l,
        bot_W1, bot_W2, top_W0, top_W1,
        wb1h, wb1l, wb2h, wb2l, wt0h, wt0l, wt1h, wt1l,
        indices, tables, tcat);

    // ---- hybrid 2: bottom l1 (256 blocks) + gather chunk 2 ----
    gemm_mfma_x3_g<1><<<256 + G2, 256, 0, stream>>>(
        b1h, b1l, wb1h, wb1l, bot_b1, nullptr, b2h, b2l,
        512, 512, 512, 256, 256,
        indices, tables, tcat, G1 * 4);

    // ---- hybrid 3: bottom l2 (64 blocks) + gather chunk 3 ----
    gemm_mfma_x3_g<0><<<64 + G3, 256, 0, stream>>>(
        b2h, b2l, wb2h, wb2l, bot_b2, tcat, nullptr, nullptr,
        256, 256, 256, NCAT * D_, 64,
        indices, tables, tcat, (G1 + G2) * 4);

    // ---- interaction -> split R ----
    interact_split<<<B_, 128, 0, stream>>>(tcat, Rh, Rl);

    // ---- top MLP (no gather blocks left; ngemm = grid) ----
    gemm_mfma_x3_g<1><<<512, 256, 0, stream>>>(
        Rh, Rl, wt0h, wt0l, top_b0, nullptr, b1h, b1l,
        RPAD, RPAD, RPAD, 512, 512,
        indices, tables, tcat, 0);
    gemm_mfma_x3_g<0><<<256, 256, 0, stream>>>(
        b1h, b1l, wt1h, wt1l, top_b1, buf2f, nullptr, nullptr,
        512, 512, 512, 256, 256,
        indices, tables, tcat, 0);
    final_layer<<<B_ / 4, 256, 0, stream>>>(buf2f, top_W2, top_b2, out);
}